// Round 6
// baseline (288.711 us; speedup 1.0000x reference)
//
#include <hip/hip_runtime.h>
#include <math.h>

#define B_   256
#define S_   512
#define NQ_  1000
#define MEM_ 20
#define DK_  50
#define DV_  200
#define FC_  50
#define RPB  2
#define CHK  8              // chunks for parallel scan
#define CLEN (S_/CHK)       // 64 steps per chunk
#define NKS  7              // K-steps for MFMA (K = 224 = 200 reads + 24 zero)
#define XS_STRIDE 232       // LDS row stride in bf16 (224 + 8 pad)
#define NB_EA    1001
#define NB_CORR  4
#define NB_WPACK 7
#define NB_HQ    251
#define PREP_BLOCKS (NB_EA+NB_CORR+NB_WPACK+NB_HQ)
#define MM_BLOCKS (B_*CHK)        // 2048
#define SCANA_BLOCKS (B_*(CHK-1)) // 1792

typedef __attribute__((ext_vector_type(8))) short bf16x8_t;
typedef __attribute__((ext_vector_type(4))) float f32x4_t;

static __device__ __forceinline__ unsigned short f2bf(float f){
  unsigned u = __float_as_uint(f);
  unsigned r = u + 0x7fffu + ((u >> 16) & 1u);   // round-to-nearest-even
  return (unsigned short)(r >> 16);
}
static __device__ __forceinline__ float bf2f_lo(unsigned v){ return __uint_as_float(v << 16); }
static __device__ __forceinline__ float bf2f_hi(unsigned v){ return __uint_as_float(v & 0xffff0000u); }
static __device__ __forceinline__ float ftanh(float x){
  float e = __expf(2.f*x);
  return 1.f - 2.f*__builtin_amdgcn_rcpf(e+1.f);
}
static __device__ __forceinline__ float fsigm(float x){
  return __builtin_amdgcn_rcpf(1.f+__expf(-x));
}

// K0: fused prep — [0,1001): eaTab; [1001,1005): corrTab; [1005,1012): WpFrag; rest: hq.
__global__ __launch_bounds__(256) void k_prep(
    const float* __restrict__ qaw,
    const float* __restrict__ ew, const float* __restrict__ eb,
    const float* __restrict__ aw, const float* __restrict__ ab,
    float2* __restrict__ eaTab,
    const float* __restrict__ qw, const float* __restrict__ mk,
    float* __restrict__ corrTab,
    const float* __restrict__ rw, const float* __restrict__ rb,
    const float* __restrict__ pw,
    unsigned short* __restrict__ WpFrag, float* __restrict__ pwPad,
    float* __restrict__ hq){
  __shared__ float qa[RPB*DV_];
  int blk = blockIdx.x;
  if(blk < NB_EA){
    int row0 = blk*RPB;
    for(int i=threadIdx.x; i<RPB*DV_; i+=256){
      int r = i/DV_, cc = i - r*DV_;
      int row = row0 + r;
      qa[i] = (row <= 2*NQ_) ? qaw[row*DV_+cc] : 0.f;
    }
    __syncthreads();
    int d = threadIdx.x;
    if(d >= DV_) return;
    float accE[RPB], accA[RPB];
    #pragma unroll
    for(int r=0;r<RPB;++r){ accE[r] = eb[d]; accA[r] = ab[d]; }
    for(int j=0;j<DV_;++j){
      float we = ew[j*DV_+d], wa = aw[j*DV_+d];
      #pragma unroll
      for(int r=0;r<RPB;++r){
        float x = qa[r*DV_+j];
        accE[r] = fmaf(x, we, accE[r]);
        accA[r] = fmaf(x, wa, accA[r]);
      }
    }
    #pragma unroll
    for(int r=0;r<RPB;++r){
      int row = row0 + r;
      if(row <= 2*NQ_)
        eaTab[(size_t)row*DV_+d] = make_float2(fsigm(accE[r]), ftanh(accA[r]));
    }
  } else if(blk < NB_EA+NB_CORR){
    int q = (blk-NB_EA)*256 + threadIdx.x;
    if(q > NQ_) return;
    float qv[DK_];
    #pragma unroll
    for(int j=0;j<DK_;++j) qv[j] = qw[q*DK_+j];
    float s[MEM_]; float mx = -1e30f;
    #pragma unroll
    for(int m=0;m<MEM_;++m){
      float acc = 0.f;
      #pragma unroll
      for(int j=0;j<DK_;++j) acc = fmaf(qv[j], mk[m*DK_+j], acc);
      s[m] = acc; mx = fmaxf(mx, acc);
    }
    float sum = 0.f;
    #pragma unroll
    for(int m=0;m<MEM_;++m){ s[m] = __expf(s[m]-mx); sum += s[m]; }
    float inv = __builtin_amdgcn_rcpf(sum);
    #pragma unroll
    for(int m=0;m<MEM_;++m) corrTab[q*MEM_+m] = s[m]*inv;
  } else if(blk < NB_EA+NB_CORR+NB_WPACK){
    int ks = blk - (NB_EA+NB_CORR);          // 0..6
    int nt = threadIdx.x >> 6;
    int lane = threadIdx.x & 63;
    int quad = lane >> 4, col = lane & 15;
    int n = nt*16 + col;
    unsigned short tmp[8];
    #pragma unroll
    for(int j=0;j<8;++j){
      int k = ks*32 + quad*8 + j;
      tmp[j] = (k < DV_ && n < FC_) ? f2bf(rw[k*FC_+n]) : (unsigned short)0;
    }
    uint4* dst = reinterpret_cast<uint4*>(WpFrag + ((size_t)(ks*4+nt)*64 + lane)*8);
    *dst = *reinterpret_cast<const uint4*>(tmp);
    if(ks == 0 && threadIdx.x < 64)
      pwPad[threadIdx.x] = (threadIdx.x < FC_) ? pw[threadIdx.x] : 0.f;
  } else {
    int idx = (blk-(NB_EA+NB_CORR+NB_WPACK))*256 + threadIdx.x;
    int q = idx >> 6, n = idx & 63;
    if(q > NQ_) return;
    float v = 0.f;
    if(n < FC_){
      float acc = rb[n];
      #pragma unroll
      for(int j=0;j<DK_;++j)
        acc = fmaf(qw[q*DK_+j], rw[(DV_+j)*FC_+n], acc);
      v = acc;
    }
    hq[q*64+n] = v;
  }
}

// K1: phase 1 — per-chunk affine (A,B) per (b,m,d), bf16-packed. Last chunk skipped.
__global__ __launch_bounds__(256) void k_scanA(const int* __restrict__ qd,
    const int* __restrict__ qad,
    const float4* __restrict__ corr4,
    const float2* __restrict__ eaTab,
    unsigned* __restrict__ ABu){
  const int blk = blockIdx.x;
  const int b = blk / (CHK-1), c = blk % (CHK-1);
  const int d = threadIdx.x;
  const int dc = (d < DV_) ? d : DV_-1;
  const bool act = (d < DV_);
  const int* __restrict__ qp  = qd  + b*S_ + c*CLEN;
  const int* __restrict__ qap = qad + b*S_ + c*CLEN;

  float A[MEM_], Bv[MEM_];
  #pragma unroll
  for(int m=0;m<MEM_;++m){ A[m] = 1.f; Bv[m] = 0.f; }

  int q2  = qp[1];
  int qa2 = qap[1];
  int q1  = qp[0];
  int qa1 = qap[0];
  float4 c0 = corr4[q1*5+0], c1 = corr4[q1*5+1], c2 = corr4[q1*5+2],
         c3 = corr4[q1*5+3], c4 = corr4[q1*5+4];
  float2 ea = eaTab[(size_t)qa1*DV_ + dc];

  #pragma unroll 2
  for(int t=0;t<CLEN;++t){
    int t2 = (t+2 < CLEN) ? t+2 : CLEN-1;
    int q3 = qp[t2], qa3 = qap[t2];
    float4 n0 = corr4[q2*5+0], n1 = corr4[q2*5+1], n2 = corr4[q2*5+2],
           n3 = corr4[q2*5+3], n4 = corr4[q2*5+4];
    float2 ean = eaTab[(size_t)qa2*DV_ + dc];

    const float e = ea.x, a = ea.y;
    #define UPD(cv, mi) { \
      float al = fmaf(-(cv), e, 1.f); \
      float be = (cv)*a; \
      A[mi] *= al; \
      Bv[mi] = fmaf(al, Bv[mi], be); }
    UPD(c0.x, 0)  UPD(c0.y, 1)  UPD(c0.z, 2)  UPD(c0.w, 3)
    UPD(c1.x, 4)  UPD(c1.y, 5)  UPD(c1.z, 6)  UPD(c1.w, 7)
    UPD(c2.x, 8)  UPD(c2.y, 9)  UPD(c2.z,10)  UPD(c2.w,11)
    UPD(c3.x,12)  UPD(c3.y,13)  UPD(c3.z,14)  UPD(c3.w,15)
    UPD(c4.x,16)  UPD(c4.y,17)  UPD(c4.z,18)  UPD(c4.w,19)
    #undef UPD

    c0=n0; c1=n1; c2=n2; c3=n3; c4=n4; ea=ean;
    q2=q3; qa2=qa3;
  }
  if(act){
    unsigned* base = ABu + ((size_t)(b*(CHK-1) + c)*MEM_)*DV_ + d;
    #pragma unroll
    for(int m=0;m<MEM_;++m)
      base[(size_t)m*DV_] = (unsigned)f2bf(A[m]) | ((unsigned)f2bf(Bv[m]) << 16);
  }
}

// K2: prefix — compose chunk transforms; write each chunk's START Mv as ushort (bf16).
__global__ __launch_bounds__(256) void k_prefix(const float* __restrict__ mv0,
    const unsigned* __restrict__ ABu, unsigned short* __restrict__ Mv0s){
  int i = blockIdx.x*256 + threadIdx.x;
  if(i >= B_*MEM_*DV_) return;
  int d = i % DV_;
  int m = (i / DV_) % MEM_;
  int b = i / (DV_*MEM_);
  unsigned abv[CHK-1];
  #pragma unroll
  for(int c=0;c<CHK-1;++c)
    abv[c] = ABu[((size_t)(b*(CHK-1) + c)*MEM_ + m)*DV_ + d];
  float Mv = mv0[m*DV_+d];
  #pragma unroll
  for(int c=0;c<CHK;++c){
    Mv0s[((size_t)(b*CHK + c)*MEM_ + m)*DV_ + d] = f2bf(Mv);
    if(c < CHK-1) Mv = fmaf(bf2f_lo(abv[c]), Mv, bf2f_hi(abv[c]));
  }
}

// K3: fused phase-2 scan + MFMA readout + epilogue + last-block finalize.
__global__ __launch_bounds__(256) void k_scan_mm(const int* __restrict__ qd,
    const int* __restrict__ qad,
    const float4* __restrict__ corr4,
    const float2* __restrict__ eaTab,
    const unsigned short* __restrict__ Mv0s,
    const unsigned short* __restrict__ WpFrag,
    const float* __restrict__ hq,
    const float* __restrict__ pwPad, const float* __restrict__ pb,
    const float* __restrict__ target,
    float* __restrict__ out,
    float* __restrict__ pbce, float* __restrict__ pcnt,
    unsigned* __restrict__ counter){
  __shared__ unsigned short Xs[CLEN*XS_STRIDE];   // 29,696 B
  __shared__ float sbce[8];
  __shared__ int lastBlk;

  const int blk = blockIdx.x;
  const int b = blk >> 3, c = blk & (CHK-1);
  const int d = threadIdx.x;
  const int dc = (d < DV_) ? d : DV_-1;
  const bool act = (d < DV_);
  const bool padw = (d < 224);
  const int* __restrict__ qp  = qd  + b*S_ + c*CLEN;
  const int* __restrict__ qap = qad + b*S_ + c*CLEN;

  float Mv[MEM_];
  {
    const unsigned short* base = Mv0s + ((size_t)(b*CHK + c)*MEM_)*DV_ + dc;
    #pragma unroll
    for(int m=0;m<MEM_;++m) Mv[m] = bf2f_lo((unsigned)base[(size_t)m*DV_]);
  }

  int q2  = qp[1];
  int qa2 = qap[1];
  int q1  = qp[0];
  int qa1 = qap[0];
  float4 c0 = corr4[q1*5+0], c1 = corr4[q1*5+1], c2 = corr4[q1*5+2],
         c3 = corr4[q1*5+3], c4 = corr4[q1*5+4];
  float2 ea = eaTab[(size_t)qa1*DV_ + dc];

  #pragma unroll 2
  for(int t=0;t<CLEN;++t){
    int t2 = (t+2 < CLEN) ? t+2 : CLEN-1;
    int q3 = qp[t2], qa3 = qap[t2];
    float4 n0 = corr4[q2*5+0], n1 = corr4[q2*5+1], n2 = corr4[q2*5+2],
           n3 = corr4[q2*5+3], n4 = corr4[q2*5+4];
    float2 ean = eaTab[(size_t)qa2*DV_ + dc];

    const float e = ea.x, a = ea.y;
    float rd = 0.f;
    #define UPD(cv, mi) \
      rd = fmaf(cv, Mv[mi], rd); \
      Mv[mi] = fmaf(cv, fmaf(-Mv[mi], e, a), Mv[mi]);
    UPD(c0.x, 0)  UPD(c0.y, 1)  UPD(c0.z, 2)  UPD(c0.w, 3)
    UPD(c1.x, 4)  UPD(c1.y, 5)  UPD(c1.z, 6)  UPD(c1.w, 7)
    UPD(c2.x, 8)  UPD(c2.y, 9)  UPD(c2.z,10)  UPD(c2.w,11)
    UPD(c3.x,12)  UPD(c3.y,13)  UPD(c3.z,14)  UPD(c3.w,15)
    UPD(c4.x,16)  UPD(c4.y,17)  UPD(c4.z,18)  UPD(c4.w,19)
    #undef UPD

    if(padw) Xs[t*XS_STRIDE + d] = act ? f2bf(rd) : (unsigned short)0;

    c0=n0; c1=n1; c2=n2; c3=n3; c4=n4; ea=ean;
    q2=q3; qa2=qa3;
  }
  __syncthreads();

  // ---- MFMA phase: wave w owns rows w*16..w*16+15, all 4 n-tiles ----
  const int wave = threadIdx.x >> 6;
  const int lane = threadIdx.x & 63;
  const int col  = lane & 15, quad = lane >> 4;
  const int mbase = wave*16;

  f32x4_t acc[4];
  #pragma unroll
  for(int nt=0;nt<4;++nt) acc[nt] = (f32x4_t){0.f,0.f,0.f,0.f};

  #pragma unroll
  for(int ks=0;ks<NKS;++ks){
    bf16x8_t a = *reinterpret_cast<const bf16x8_t*>(Xs + (mbase+col)*XS_STRIDE + quad*8 + ks*32);
    #pragma unroll
    for(int nt=0;nt<4;++nt){
      bf16x8_t bfr = *reinterpret_cast<const bf16x8_t*>(WpFrag + ((size_t)(ks*4+nt)*64 + lane)*8);
      acc[nt] = __builtin_amdgcn_mfma_f32_16x16x32_bf16(a, bfr, acc[nt], 0, 0, 0);
    }
  }

  // epilogue: h += hq[q]; part = sum_n pw[n]*tanh(h); reduce over col lanes
  float part[4];
  #pragma unroll
  for(int reg=0;reg<4;++reg){
    int mloc = mbase + quad*4 + reg;
    int q = qp[mloc];
    float s = 0.f;
    #pragma unroll
    for(int nt=0;nt<4;++nt){
      int n = nt*16 + col;
      float h = acc[nt][reg] + hq[q*64 + n];
      s = fmaf(pwPad[n], ftanh(h), s);
    }
    part[reg] = s;
  }
  #pragma unroll
  for(int off=1; off<16; off<<=1){
    #pragma unroll
    for(int reg=0;reg<4;++reg) part[reg] += __shfl_xor(part[reg], off, 64);
  }

  float bce = 0.f, cnt = 0.f;
  if(col == 0){
    float pbv = pb[0];
    #pragma unroll
    for(int reg=0;reg<4;++reg){
      int mloc = mbase + quad*4 + reg;
      int row = b*S_ + c*CLEN + mloc;
      float logit = part[reg] + pbv;
      out[1+row] = fsigm(logit);
      float t = target[row];
      if(t >= 0.f){
        cnt += 1.f;
        bce += fmaxf(logit,0.f) - logit*t + log1pf(__expf(-fabsf(logit)));
      }
    }
  }
  bce += __shfl_xor(bce, 16, 64); cnt += __shfl_xor(cnt, 16, 64);
  bce += __shfl_xor(bce, 32, 64); cnt += __shfl_xor(cnt, 32, 64);
  if(lane == 0){ sbce[wave] = bce; sbce[4+wave] = cnt; }
  __syncthreads();

  if(threadIdx.x == 0){
    float tb = sbce[0]+sbce[1]+sbce[2]+sbce[3];
    float tc = sbce[4]+sbce[5]+sbce[6]+sbce[7];
    __hip_atomic_store(&pbce[blk], tb, __ATOMIC_RELAXED, __HIP_MEMORY_SCOPE_AGENT);
    __hip_atomic_store(&pcnt[blk], tc, __ATOMIC_RELAXED, __HIP_MEMORY_SCOPE_AGENT);
    __threadfence();
    unsigned old = __hip_atomic_fetch_add(counter, 1u, __ATOMIC_ACQ_REL, __HIP_MEMORY_SCOPE_AGENT);
    lastBlk = (old == MM_BLOCKS-1);
  }
  __syncthreads();

  if(lastBlk){
    float rb_ = 0.f, rc_ = 0.f;
    for(int i=threadIdx.x; i<MM_BLOCKS; i+=256){
      rb_ += __hip_atomic_load(&pbce[i], __ATOMIC_RELAXED, __HIP_MEMORY_SCOPE_AGENT);
      rc_ += __hip_atomic_load(&pcnt[i], __ATOMIC_RELAXED, __HIP_MEMORY_SCOPE_AGENT);
    }
    #pragma unroll
    for(int off=32; off>0; off>>=1){
      rb_ += __shfl_down(rb_, off, 64);
      rc_ += __shfl_down(rc_, off, 64);
    }
    __shared__ float fb[4], fc[4];
    int w = threadIdx.x >> 6;
    if((threadIdx.x & 63) == 0){ fb[w] = rb_; fc[w] = rc_; }
    __syncthreads();
    if(threadIdx.x == 0){
      float Bt = fb[0]+fb[1]+fb[2]+fb[3];
      float Ct = fc[0]+fc[1]+fc[2]+fc[3];
      out[0] = Bt / fmaxf(Ct, 1.f);
    }
  }
}

extern "C" void kernel_launch(void* const* d_in, const int* in_sizes, int n_in,
                              void* d_out, int out_size, void* d_ws, size_t ws_size,
                              hipStream_t stream){
  const int*   qd     = (const int*)d_in[0];
  const int*   qad    = (const int*)d_in[1];
  const float* target = (const float*)d_in[2];
  const float* qw     = (const float*)d_in[3];
  const float* qaw    = (const float*)d_in[4];
  const float* mk     = (const float*)d_in[5];
  const float* mv0    = (const float*)d_in[6];
  const float* ew     = (const float*)d_in[7];
  const float* eb     = (const float*)d_in[8];
  const float* aw     = (const float*)d_in[9];
  const float* ab     = (const float*)d_in[10];
  const float* rw     = (const float*)d_in[11];
  const float* rb     = (const float*)d_in[12];
  const float* pw     = (const float*)d_in[13];
  const float* pb     = (const float*)d_in[14];
  float* out = (float*)d_out;

  char* ws = (char*)d_ws;
  size_t off = 0;
  unsigned* counter = (unsigned*)(ws + off);         off += 256;
  float* pbce     = (float*)(ws + off);              off += (size_t)MM_BLOCKS*4;
  float* pcnt     = (float*)(ws + off);              off += (size_t)MM_BLOCKS*4;
  float* corrTab  = (float*)(ws + off);              off += (((size_t)(NQ_+1)*MEM_*4 + 255)/256)*256;
  float2* eaTab   = (float2*)(ws + off);             off += (((size_t)(2*NQ_+1)*DV_*8 + 255)/256)*256;
  unsigned* ABu   = (unsigned*)(ws + off);           off += (size_t)SCANA_BLOCKS*MEM_*DV_*4;
  unsigned short* Mv0s = (unsigned short*)(ws + off); off += (size_t)MM_BLOCKS*MEM_*DV_*2;
  unsigned short* WpFrag = (unsigned short*)(ws + off); off += ((size_t)NKS*4*64*8*2 + 255)/256*256;
  float* pwPad    = (float*)(ws + off);              off += 256;
  float* hq       = (float*)(ws + off);              off += (size_t)(NQ_+1)*64*4;

  hipMemsetAsync(counter, 0, sizeof(unsigned), stream);
  k_prep<<<dim3(PREP_BLOCKS), dim3(256), 0, stream>>>(qaw, ew, eb, aw, ab, eaTab,
                                                      qw, mk, corrTab,
                                                      rw, rb, pw, WpFrag, pwPad, hq);
  k_scanA<<<dim3(SCANA_BLOCKS), dim3(256), 0, stream>>>(qd, qad, (const float4*)corrTab, (const float2*)eaTab, ABu);
  k_prefix<<<dim3((B_*MEM_*DV_+255)/256), dim3(256), 0, stream>>>(mv0, ABu, Mv0s);
  k_scan_mm<<<dim3(MM_BLOCKS), dim3(256), 0, stream>>>(qd, qad, (const float4*)corrTab, (const float2*)eaTab,
                                                       Mv0s, WpFrag, hq, pwPad, pb, target, out,
                                                       pbce, pcnt, counter);
}